// Round 4
// baseline (175.586 us; speedup 1.0000x reference)
//
#include <hip/hip_runtime.h>
#include <stdint.h>

// Problem constants (match reference)
#define N_Q   50000
#define N_S   100000
#define KNB   32
#define NKP   27
#define CH    64            // IN == OUT == 64
#define KP_EXT 0.057735026918962584f   // 2*0.1/(KP-1)/sqrt(3)
#define BBOX  0.158f                    // 0.1 + KP_EXT + margin
#define NEG_SLOPE 0.01f

// ---------------------------------------------------------------------------
// One wave (64 lanes) per query point.
//   Phase 0: sniff whether `inds` is int32 or int64 (little-endian) layout.
//            int64 values here are in [0, 100000) so every high dword is 0;
//            4 zero-checks at odd int32 positions distinguish the layouts
//            with P(false positive) ~ 1e-20 for random int32 indices.
//   Phase 1 (lanes 0..31): test the query's 32 neighbors for any nonzero
//            kernel-point correlation (bbox reject, then exact 27-pt test).
//   Phase 2 (all 64 lanes, per surviving neighbor): cooperative GEMVs:
//            f   = leaky_relu(x[s,:] @ W_pre + b_pre)   (shfl-broadcast)
//            acc += sum_{l: w_l>0} w_l * (f @ kp_w[l])
//   Store out[n,:] exactly once (no atomics, no pre-zeroing, no workspace).
// ---------------------------------------------------------------------------
__global__ __launch_bounds__(256) void kpconv_kernel(
    const float* __restrict__ q_pts,    // [N_Q,3]
    const float* __restrict__ s_pts,    // [N_S,3]
    const int*   __restrict__ inds,     // [N_Q,KNB] int32 OR int64 (sniffed)
    const float* __restrict__ x,        // [N_S,CH]
    const float* __restrict__ W_pre,    // [CH,CH]
    const float* __restrict__ b_pre,    // [CH]
    const float* __restrict__ kp_w,     // [NKP,CH,CH]
    const float* __restrict__ kpts,     // [NKP,3]
    float* __restrict__ out)            // [N_Q,CH]
{
    const int lane = threadIdx.x & 63;
    const int n = (int)((blockIdx.x * (unsigned)blockDim.x + threadIdx.x) >> 6);
    if (n >= N_Q) return;

    // ---- Phase 0: dtype sniff (wave-uniform scalar loads, L2-hot) ----
    const bool i64 = (inds[1] == 0) & (inds[3] == 0) & (inds[5] == 0) & (inds[7] == 0);

    const float qx = q_pts[n * 3 + 0];
    const float qy = q_pts[n * 3 + 1];
    const float qz = q_pts[n * 3 + 2];

    const float e2 = KP_EXT * KP_EXT;

    // ---- Phase 1: per-lane neighbor test (lanes 0..31) ----
    int   idx = 0;
    float rx = 0.f, ry = 0.f, rz = 0.f;
    bool  hit = false;

    if (lane < KNB) {
        long p = (long)n * KNB + lane;          // flat pair index
        long off = i64 ? (2 * p) : p;           // low dword if int64 (LE)
        int v = inds[off];
        int m = N_S + 1;                         // python-style mod (shadow = N_S)
        idx = v % m; if (idx < 0) idx += m;
        if (idx < N_S) {
            rx = s_pts[idx * 3 + 0] - qx;
            ry = s_pts[idx * 3 + 1] - qy;
            rz = s_pts[idx * 3 + 2] - qz;
            if (fabsf(rx) <= BBOX && fabsf(ry) <= BBOX && fabsf(rz) <= BBOX) {
                #pragma unroll 1
                for (int l = 0; l < NKP; ++l) {
                    float dx = rx - kpts[l * 3 + 0];
                    float dy = ry - kpts[l * 3 + 1];
                    float dz = rz - kpts[l * 3 + 2];
                    if (dx * dx + dy * dy + dz * dz < e2) { hit = true; break; }
                }
            }
        }
    }

    unsigned long long mask = __ballot(hit);

    float acc = 0.f;

    // ---- Phase 2: cooperative accumulation per surviving neighbor ----
    while (mask) {
        int src = __ffsll((long long)mask) - 1;
        mask &= mask - 1;

        int   s_idx = __shfl(idx, src, 64);
        float rxs   = __shfl(rx, src, 64);
        float rys   = __shfl(ry, src, 64);
        float rzs   = __shfl(rz, src, 64);

        // preactivation GEMV: f[lane] = leaky_relu(b + sum_i x[s,i]*W_pre[i,lane])
        float xr = x[(long)s_idx * CH + lane];
        float f  = b_pre[lane];
        #pragma unroll
        for (int i = 0; i < CH; ++i) {
            float xi = __shfl(xr, i, 64);
            f = fmaf(xi, W_pre[i * CH + lane], f);
        }
        f = (f >= 0.f) ? f : NEG_SLOPE * f;

        // kernel-point loop (wave-uniform branches; <=2 typically active)
        #pragma unroll 1
        for (int l = 0; l < NKP; ++l) {
            float dx = rxs - kpts[l * 3 + 0];
            float dy = rys - kpts[l * 3 + 1];
            float dz = rzs - kpts[l * 3 + 2];
            float d2 = dx * dx + dy * dy + dz * dz;
            if (d2 < e2) {
                float w = 1.f - sqrtf(d2) / KP_EXT;   // > 0 here
                const float* Wl = kp_w + (long)l * CH * CH;
                float partial = 0.f;
                #pragma unroll
                for (int i = 0; i < CH; ++i) {
                    float fi = __shfl(f, i, 64);
                    partial = fmaf(fi, Wl[i * CH + lane], partial);
                }
                acc = fmaf(w, partial, acc);
            }
        }
    }

    out[(long)n * CH + lane] = acc;      // coalesced row store, written once
}

// ---------------------------------------------------------------------------
extern "C" void kernel_launch(void* const* d_in, const int* in_sizes, int n_in,
                              void* d_out, int out_size, void* d_ws, size_t ws_size,
                              hipStream_t stream)
{
    const float* q_pts = (const float*)d_in[0];
    const float* s_pts = (const float*)d_in[1];
    const int*   inds  = (const int*)  d_in[2];
    const float* x     = (const float*)d_in[3];
    const float* W_pre = (const float*)d_in[4];
    const float* b_pre = (const float*)d_in[5];
    const float* kp_w  = (const float*)d_in[6];
    const float* kpts  = (const float*)d_in[7];
    float* out = (float*)d_out;

    // one wave per query: N_Q waves, 4 waves per 256-thread block
    int blocks = (N_Q + 3) / 4;          // 12500
    kpconv_kernel<<<blocks, 256, 0, stream>>>(q_pts, s_pts, inds, x,
                                              W_pre, b_pre, kp_w, kpts, out);
}

// Round 5
// 153.489 us; speedup vs baseline: 1.1440x; 1.1440x over previous
//
#include <hip/hip_runtime.h>
#include <stdint.h>

// Problem constants (match reference)
#define N_Q   50000
#define N_S   100000
#define KNB   32
#define NKP   27
#define CH    64            // IN == OUT == 64
#define KP_EXT 0.057735026918962584f   // 2*0.1/(KP-1)/sqrt(3)
#define BBOX  0.158f                    // 0.1 + KP_EXT + margin
#define NEG_SLOPE 0.01f
#define NJOB  (N_Q / 2)     // 25000 jobs; each job = 2 queries = 64 pairs

// ---------------------------------------------------------------------------
// Persistent-wave KPConv. Counters (r4) showed latency-bound: hbm 3%,
// VALU 7%, occupancy 14% -> pay down the dependent-load chain, not BW.
//   - 4096 persistent waves, each loops over ~6 jobs (2 queries each).
//   - job j+1's inds/q_pts loads issued before job j is processed.
//   - all 64 lanes active in the neighbor test (2 queries x 32 neighbors).
//   - int32/int64 layout sniff hoisted to once per wave.
//   - W_pre/b_pre/kpts in LDS (phase-2 GEMVs never touch global weights
//     except the 1-2 active kp_w panels, which are L2-hot).
// ---------------------------------------------------------------------------
__global__ __launch_bounds__(256) void kpconv_kernel(
    const float* __restrict__ q_pts,    // [N_Q,3]
    const float* __restrict__ s_pts,    // [N_S,3]
    const int*   __restrict__ inds,     // [N_Q,KNB] int32 OR int64 (sniffed)
    const float* __restrict__ x,        // [N_S,CH]
    const float* __restrict__ W_pre,    // [CH,CH]
    const float* __restrict__ b_pre,    // [CH]
    const float* __restrict__ kp_w,     // [NKP,CH,CH]
    const float* __restrict__ kpts,     // [NKP,3]
    float* __restrict__ out)            // [N_Q,CH]
{
    __shared__ float sW[CH * CH];       // 16 KB
    __shared__ float sB[CH];
    __shared__ float sKP[NKP * 3];

    for (int i = threadIdx.x; i < CH * CH; i += 256) sW[i] = W_pre[i];
    if (threadIdx.x < CH)      sB[threadIdx.x]  = b_pre[threadIdx.x];
    if (threadIdx.x < NKP * 3) sKP[threadIdx.x] = kpts[threadIdx.x];
    __syncthreads();

    const int lane = threadIdx.x & 63;
    const int gw   = blockIdx.x * (blockDim.x >> 6) + (threadIdx.x >> 6);
    const int nw   = gridDim.x * (blockDim.x >> 6);

    // layout sniff: int64 (LE) => high dwords of elems 0..3 are all zero.
    // For genuine int32 indices P(all four == 0) ~ 1e-20.
    const bool i64 = (inds[1] == 0) & (inds[3] == 0) & (inds[5] == 0) & (inds[7] == 0);
    const float e2 = KP_EXT * KP_EXT;

    // ---- software-pipelined job loop ----
    int j = gw;
    int   v_pf = 0;
    float qx_pf = 0.f, qy_pf = 0.f, qz_pf = 0.f;
    if (j < NJOB) {
        long fp = (long)j * 64 + lane;              // flat pair index
        v_pf = inds[i64 ? 2 * fp : fp];             // low dword if int64
        long qb = ((long)2 * j + (lane >> 5)) * 3;  // query 2j (lanes<32) / 2j+1
        qx_pf = q_pts[qb + 0];
        qy_pf = q_pts[qb + 1];
        qz_pf = q_pts[qb + 2];
    }

    while (j < NJOB) {
        const int   v  = v_pf;
        const float qx = qx_pf, qy = qy_pf, qz = qz_pf;

        const int jn = j + nw;
        if (jn < NJOB) {                            // prefetch next job
            long fp = (long)jn * 64 + lane;
            v_pf = inds[i64 ? 2 * fp : fp];
            long qb = ((long)2 * jn + (lane >> 5)) * 3;
            qx_pf = q_pts[qb + 0];
            qy_pf = q_pts[qb + 1];
            qz_pf = q_pts[qb + 2];
        }

        // ---- neighbor test: all 64 lanes (2 queries x 32 neighbors) ----
        const int m_ = N_S + 1;                     // python-style mod
        int idx = v % m_; if (idx < 0) idx += m_;
        float rx = 0.f, ry = 0.f, rz = 0.f;
        bool hit = false;
        if (idx < N_S) {                            // not the shadow point
            float sx = s_pts[idx * 3 + 0];
            float sy = s_pts[idx * 3 + 1];
            float sz = s_pts[idx * 3 + 2];
            rx = sx - qx; ry = sy - qy; rz = sz - qz;
            if (fabsf(rx) <= BBOX && fabsf(ry) <= BBOX && fabsf(rz) <= BBOX) {
                #pragma unroll 1
                for (int l = 0; l < NKP; ++l) {
                    float dx = rx - sKP[l * 3 + 0];
                    float dy = ry - sKP[l * 3 + 1];
                    float dz = rz - sKP[l * 3 + 2];
                    if (dx * dx + dy * dy + dz * dz < e2) { hit = true; break; }
                }
            }
        }

        const unsigned long long mask = __ballot(hit);

        // ---- per-query accumulation (rare: ~8.6% of queries have hits) ----
        #pragma unroll 1
        for (int h = 0; h < 2; ++h) {
            unsigned long long mh = h ? (mask >> 32)
                                      : (mask & 0xFFFFFFFFull);
            float acc = 0.f;
            while (mh) {
                int src = (__ffsll((long long)mh) - 1) + (h << 5);
                mh &= mh - 1;

                int   s_idx = __shfl(idx, src, 64);
                float rxs   = __shfl(rx, src, 64);
                float rys   = __shfl(ry, src, 64);
                float rzs   = __shfl(rz, src, 64);

                // preactivation GEMV (W_pre from LDS, broadcast reads)
                float xr = x[(long)s_idx * CH + lane];
                float f  = sB[lane];
                #pragma unroll
                for (int i = 0; i < CH; ++i) {
                    float xi = __shfl(xr, i, 64);
                    f = fmaf(xi, sW[i * CH + lane], f);
                }
                f = (f >= 0.f) ? f : NEG_SLOPE * f;

                // kernel-point loop (wave-uniform; <=2 typically active)
                #pragma unroll 1
                for (int l = 0; l < NKP; ++l) {
                    float dx = rxs - sKP[l * 3 + 0];
                    float dy = rys - sKP[l * 3 + 1];
                    float dz = rzs - sKP[l * 3 + 2];
                    float d2 = dx * dx + dy * dy + dz * dz;
                    if (d2 < e2) {
                        float w = 1.f - sqrtf(d2) / KP_EXT;   // > 0 here
                        const float* Wl = kp_w + (long)l * CH * CH;
                        float partial = 0.f;
                        #pragma unroll
                        for (int i = 0; i < CH; ++i) {
                            float fi = __shfl(f, i, 64);
                            partial = fmaf(fi, Wl[i * CH + lane], partial);
                        }
                        acc = fmaf(w, partial, acc);
                    }
                }
            }
            out[((long)2 * j + h) * CH + lane] = acc;   // coalesced, once
        }

        j = jn;
    }
}

// ---------------------------------------------------------------------------
extern "C" void kernel_launch(void* const* d_in, const int* in_sizes, int n_in,
                              void* d_out, int out_size, void* d_ws, size_t ws_size,
                              hipStream_t stream)
{
    const float* q_pts = (const float*)d_in[0];
    const float* s_pts = (const float*)d_in[1];
    const int*   inds  = (const int*)  d_in[2];
    const float* x     = (const float*)d_in[3];
    const float* W_pre = (const float*)d_in[4];
    const float* b_pre = (const float*)d_in[5];
    const float* kp_w  = (const float*)d_in[6];
    const float* kpts  = (const float*)d_in[7];
    float* out = (float*)d_out;

    // persistent grid: 1024 blocks x 256 = 4096 waves (~16/CU), each ~6 jobs
    kpconv_kernel<<<1024, 256, 0, stream>>>(q_pts, s_pts, inds, x,
                                            W_pre, b_pre, kp_w, kpts, out);
}